// Round 12
// baseline (475.986 us; speedup 1.0000x reference)
//
#include <hip/hip_runtime.h>
#include <hip/hip_bf16.h>
#include <math.h>

#define S_LEN 2048
#define BATCH 4
#define HDIM 768
#define LOUT 9
#define NROWS (BATCH*S_LEN)
#define K2H 1536
#define KHALF 768
#define WIN 11
#define NEG_INF_F (-1e30f)
#define NBLK 768
#define NWAVE (NBLK*4)

typedef __attribute__((ext_vector_type(4))) float f32x4;
typedef __attribute__((ext_vector_type(8))) short bf16x8;

static __device__ __forceinline__ void async_ld16(const void* g, void* l) {
  __builtin_amdgcn_global_load_lds((const __attribute__((address_space(1))) void*)g,
                                   (__attribute__((address_space(3))) void*)l, 16, 0, 0);
}

static __device__ __forceinline__ unsigned short f2bf(float f) {
  union { float f; unsigned int u; } v; v.f = f;
  unsigned int u = v.u;
  unsigned int r = (u + 0x7fffu + ((u >> 16) & 1u)) >> 16;
  return (unsigned short)r;
}

static __device__ __forceinline__ float bf2f(unsigned short h) {
  union { unsigned int u; float f; } v; v.u = ((unsigned int)h) << 16;
  return v.f;
}

// Monotonic-counter grid barrier (no reset, no ABA). k = 1,2,3...
// All 768 blocks are co-resident (3/CU via __launch_bounds__(256,3)).
static __device__ __forceinline__ void gridbar(unsigned* cnt, unsigned k) {
  __syncthreads();
  if (threadIdx.x == 0) {
    __threadfence();                      // release: my writes visible device-wide
    atomicAdd(cnt, 1u);
    while (atomicAdd(cnt, 0u) < NBLK * k) __builtin_amdgcn_s_sleep(4);
    __threadfence();                      // acquire: invalidate stale cache lines
  }
  __syncthreads();
}

__global__ __launch_bounds__(256, 3)
void k_fused(const float* __restrict__ x,
             const float* __restrict__ Wc,
             const float* __restrict__ bc,
             const float* __restrict__ wa,
             const float* __restrict__ ba,
             const float* __restrict__ W1,
             const float* __restrict__ b1,
             const float* __restrict__ gamma,
             const float* __restrict__ beta,
             const float* __restrict__ W2,
             const float* __restrict__ b2,
             unsigned short* __restrict__ xc,
             unsigned short* __restrict__ w1t,
             float* __restrict__ scores,
             float* __restrict__ base,
             unsigned short* __restrict__ hbuf,
             unsigned* __restrict__ barcnt,
             float* __restrict__ out) {
  __shared__ float tile[32][33];                 // transpose scratch (4.2 KB)
  __shared__ unsigned short As[2][128 * 32];     // 16 KB
  __shared__ unsigned short Bs[2][128 * 32];     // 16 KB
  int lane = threadIdx.x & 63, wave = threadIdx.x >> 6;
  int gwid = blockIdx.x * 4 + wave;

  // ---------- Phase 0a: W1 [1536][768] fp32 -> W1t [768][1536] bf16 ----------
  for (int j = blockIdx.x; j < 1152; j += NBLK) {
    int bk = j % 48, bn = j / 48;
    int tc = threadIdx.x % 32, tr = threadIdx.x / 32;
    #pragma unroll
    for (int i = 0; i < 32; i += 8)
      tile[tr + i][tc] = W1[(bk*32 + tr + i) * HDIM + bn*32 + tc];
    __syncthreads();
    #pragma unroll
    for (int i = 0; i < 32; i += 8)
      w1t[(bn*32 + tr + i) * K2H + bk*32 + tc] = f2bf(tile[tc][tr + i]);
    __syncthreads();
  }

  // ---------- Phase 0b: wave-per-row prep: x->bf16, score, base logits ------
  for (int row = gwid; row < NROWS; row += NWAVE) {
    const float* xr = x + (long)row * HDIM + lane * 12;
    float xv[12];
    { const float4 a = *(const float4*)(xr);
      const float4 b4 = *(const float4*)(xr + 4);
      const float4 c4 = *(const float4*)(xr + 8);
      xv[0]=a.x; xv[1]=a.y; xv[2]=a.z; xv[3]=a.w;
      xv[4]=b4.x; xv[5]=b4.y; xv[6]=b4.z; xv[7]=b4.w;
      xv[8]=c4.x; xv[9]=c4.y; xv[10]=c4.z; xv[11]=c4.w; }
    unsigned short* dst = xc + (long)row * K2H + lane * 12;
    #pragma unroll
    for (int q = 0; q < 3; ++q) {
      ushort4 o;
      o.x = f2bf(xv[q*4+0]); o.y = f2bf(xv[q*4+1]);
      o.z = f2bf(xv[q*4+2]); o.w = f2bf(xv[q*4+3]);
      *(ushort4*)(dst + q*4) = o;
    }
    const float* war = wa + lane * 12;
    float sc = 0.f;
    #pragma unroll
    for (int q = 0; q < 3; ++q) {
      const float4 w4 = *(const float4*)(war + q*4);
      sc += xv[q*4+0]*w4.x + xv[q*4+1]*w4.y + xv[q*4+2]*w4.z + xv[q*4+3]*w4.w;
    }
    const float* wcr = Wc + (long)lane * 12 * LOUT;
    float p[LOUT] = {};
    #pragma unroll
    for (int j = 0; j < 12; ++j) {
      const float xj = xv[j];
      #pragma unroll
      for (int l = 0; l < LOUT; ++l) p[l] += xj * wcr[j * LOUT + l];
    }
    #pragma unroll
    for (int m = 1; m < 64; m <<= 1) {
      sc += __shfl_xor(sc, m);
      #pragma unroll
      for (int l = 0; l < LOUT; ++l) p[l] += __shfl_xor(p[l], m);
    }
    if (lane == 0) {
      scores[row] = sc + ba[0];
      #pragma unroll
      for (int l = 0; l < LOUT; ++l) base[row * LOUT + l] = p[l] + bc[l];
    }
  }

  gridbar(barcnt, 1);

  // ---------- Phase 1: wave-per-row window softmax + weighted ctx ----------
  for (int row = gwid; row < NROWS; row += NWAVE) {
    int b = row >> 11, s = row & 2047;
    float sw[WIN];
    int jcs[WIN];
    #pragma unroll
    for (int w = 0; w < WIN; ++w) {
      int j = s - 5 + w;
      bool valid = (j >= 0) && (j < S_LEN);
      int jc = valid ? j : (j < 0 ? 0 : S_LEN - 1);
      jcs[w] = b * S_LEN + jc;
      sw[w] = valid ? scores[b * S_LEN + jc] : NEG_INF_F;
    }
    float mx = sw[0];
    #pragma unroll
    for (int w = 1; w < WIN; ++w) mx = fmaxf(mx, sw[w]);
    float es[WIN], ssum = 0.f;
    #pragma unroll
    for (int w = 0; w < WIN; ++w) {
      es[w] = (sw[w] > -1e29f) ? __expf(sw[w] - mx) : 0.f;
      ssum += es[w];
    }
    float inv = 1.f / ssum;
    float c[12] = {};
    #pragma unroll
    for (int w = 0; w < WIN; ++w) {
      float aw = es[w] * inv;
      const unsigned short* src = xc + (long)jcs[w] * K2H + lane * 12;
      #pragma unroll
      for (int q = 0; q < 3; ++q) {
        const ushort4 uv = *(const ushort4*)(src + q*4);
        c[q*4+0] += aw * bf2f(uv.x);
        c[q*4+1] += aw * bf2f(uv.y);
        c[q*4+2] += aw * bf2f(uv.z);
        c[q*4+3] += aw * bf2f(uv.w);
      }
    }
    unsigned short* dst = xc + (long)row * K2H + HDIM + lane * 12;
    #pragma unroll
    for (int q = 0; q < 3; ++q) {
      ushort4 o;
      o.x = f2bf(c[q*4+0]); o.y = f2bf(c[q*4+1]);
      o.z = f2bf(c[q*4+2]); o.w = f2bf(c[q*4+3]);
      *(ushort4*)(dst + q*4) = o;
    }
  }

  gridbar(barcnt, 2);

  // ---------- Phase 2: split-K GEMM (R9 structure, 1 job per block) --------
  {
    int bid = blockIdx.x;
    int obid = (bid & 7) * 96 + (bid >> 3);   // XCD-bijective
    int kh = obid / 384;
    int mt = obid % 384;
    int bm = mt / 6, bn = mt % 6;
    int wm = wave >> 1, wn = wave & 1;

    int rowc = lane >> 2;
    int fST = ((lane >> 2) ^ (lane >> 4)) & 3;
    int sST = (lane & 3) ^ fST;
    const unsigned short* gA0 = xc  + (long)(bm * 128 + wave * 16 + rowc) * K2H + kh * KHALF + sST * 8;
    const unsigned short* gB0 = w1t + (long)(bn * 128 + wave * 16 + rowc) * K2H + kh * KHALF + sST * 8;

    int fR = ((lane & 3) ^ ((lane >> 2) & 3)) & 3;
    int slR = ((lane >> 4) ^ fR) & 3;
    int arow = wm * 64 + (lane & 15);
    int brow = wn * 64 + (lane & 15);

    f32x4 acc[4][4] = {};

#define STAGE(buf, kt) do {                                                    \
    async_ld16(gA0 + (kt),            &As[buf][(wave * 16) * 32]);             \
    async_ld16(gA0 + 64 * K2H + (kt), &As[buf][(64 + wave * 16) * 32]);        \
    async_ld16(gB0 + (kt),            &Bs[buf][(wave * 16) * 32]);             \
    async_ld16(gB0 + 64 * K2H + (kt), &Bs[buf][(64 + wave * 16) * 32]);        \
  } while (0)

#define COMPUTE(buf) do {                                                      \
    bf16x8 af[4], bfv[4];                                                      \
    _Pragma("unroll")                                                          \
    for (int m = 0; m < 4; ++m)                                                \
      af[m] = *(const bf16x8*)(&As[buf][(arow + m * 16) * 32 + slR * 8]);      \
    _Pragma("unroll")                                                          \
    for (int n = 0; n < 4; ++n)                                                \
      bfv[n] = *(const bf16x8*)(&Bs[buf][(brow + n * 16) * 32 + slR * 8]);     \
    _Pragma("unroll")                                                          \
    for (int m = 0; m < 4; ++m)                                                \
      _Pragma("unroll")                                                        \
      for (int n = 0; n < 4; ++n)                                              \
        acc[m][n] = __builtin_amdgcn_mfma_f32_16x16x32_bf16(af[m], bfv[n], acc[m][n], 0, 0, 0); \
  } while (0)

    STAGE(0, 0);
    __syncthreads();
    int cur = 0;
    #pragma unroll 1
    for (int tt = 0; tt < 23; ++tt) {
      STAGE(cur ^ 1, (tt + 1) * 32);
      COMPUTE(cur);
      __syncthreads();
      cur ^= 1;
    }
    COMPUTE(cur);

    unsigned short* Hp = hbuf + (long)kh * NROWS * HDIM;
    int orow = bm * 128 + wm * 64 + (lane >> 4) * 4;
    int ocol = bn * 128 + wn * 64 + (lane & 15);
    #pragma unroll
    for (int m = 0; m < 4; ++m)
      #pragma unroll
      for (int n = 0; n < 4; ++n) {
        int col = ocol + n * 16;
        #pragma unroll
        for (int r = 0; r < 4; ++r) {
          Hp[(long)(orow + m * 16 + r) * HDIM + col] = f2bf(acc[m][n][r]);
        }
      }
#undef STAGE
#undef COMPUTE
  }

  gridbar(barcnt, 3);

  // ---------- Phase 3: wave-per-row LN + GELU + W2 + combine ---------------
  const unsigned short* H0 = hbuf;
  const unsigned short* H1 = hbuf + (long)NROWS * HDIM;
  for (int row = gwid; row < NROWS; row += NWAVE) {
    const unsigned short* h0p = H0 + (long)row * HDIM + lane * 12;
    const unsigned short* h1p = H1 + (long)row * HDIM + lane * 12;
    const float* b1p = b1 + lane * 12;
    float vv[12];
    #pragma unroll
    for (int q = 0; q < 3; ++q) {
      const ushort4 a = *(const ushort4*)(h0p + q*4);
      const ushort4 b4 = *(const ushort4*)(h1p + q*4);
      const float4 bb = *(const float4*)(b1p + q*4);
      vv[q*4+0] = bf2f(a.x) + bf2f(b4.x) + bb.x;
      vv[q*4+1] = bf2f(a.y) + bf2f(b4.y) + bb.y;
      vv[q*4+2] = bf2f(a.z) + bf2f(b4.z) + bb.z;
      vv[q*4+3] = bf2f(a.w) + bf2f(b4.w) + bb.w;
    }
    float s1 = 0.f, s2 = 0.f;
    #pragma unroll
    for (int j = 0; j < 12; ++j) { s1 += vv[j]; s2 += vv[j] * vv[j]; }
    #pragma unroll
    for (int m = 1; m < 64; m <<= 1) { s1 += __shfl_xor(s1, m); s2 += __shfl_xor(s2, m); }
    float mu = s1 * (1.f / HDIM);
    float var = s2 * (1.f / HDIM) - mu * mu;
    float rstd = rsqrtf(var + 1e-5f);
    const float* gp = gamma + lane * 12;
    const float* bp = beta + lane * 12;
    const float* w2r = W2 + (long)lane * 12 * LOUT;
    float p[LOUT] = {};
    #pragma unroll
    for (int q = 0; q < 3; ++q) {
      const float4 g4 = *(const float4*)(gp + q*4);
      const float4 be4 = *(const float4*)(bp + q*4);
      const float gv[4] = { g4.x, g4.y, g4.z, g4.w };
      const float bvv[4] = { be4.x, be4.y, be4.z, be4.w };
      #pragma unroll
      for (int k2 = 0; k2 < 4; ++k2) {
        int j = q*4 + k2;
        float g = (vv[j] - mu) * rstd * gv[k2] + bvv[k2];
        float gg = 0.5f * g * (1.f + erff(g * 0.70710678118654752f));
        #pragma unroll
        for (int l = 0; l < LOUT; ++l) p[l] += gg * w2r[j * LOUT + l];
      }
    }
    #pragma unroll
    for (int m = 1; m < 64; m <<= 1)
      #pragma unroll
      for (int l = 0; l < LOUT; ++l) p[l] += __shfl_xor(p[l], m);
    if (lane == 0) {
      #pragma unroll
      for (int l = 0; l < LOUT; ++l) {
        out[row * LOUT + l] = 0.5f * base[row * LOUT + l] + 0.5f * (p[l] + b2[l]);
      }
    }
  }
}

extern "C" void kernel_launch(void* const* d_in, const int* in_sizes, int n_in,
                              void* d_out, int out_size, void* d_ws, size_t ws_size,
                              hipStream_t stream) {
  const float* x     = (const float*)d_in[0];
  const float* Wc    = (const float*)d_in[1];
  const float* bc    = (const float*)d_in[2];
  const float* wa    = (const float*)d_in[3];
  const float* ba    = (const float*)d_in[4];
  const float* W1    = (const float*)d_in[5];
  const float* b1    = (const float*)d_in[6];
  const float* gamma = (const float*)d_in[7];
  const float* beta  = (const float*)d_in[8];
  const float* W2    = (const float*)d_in[9];
  const float* b2    = (const float*)d_in[10];
  float* out = (float*)d_out;

  char* ws = (char*)d_ws;
  unsigned short* xc   = (unsigned short*)(ws);             // 8192*1536*2  = 25,165,824
  unsigned short* w1t  = (unsigned short*)(ws + 25165824);  // 768*1536*2   =  2,359,296
  float* scores        = (float*)(ws + 27525120);           // 8192*4       =     32,768
  float* base          = (float*)(ws + 27557888);           // 8192*9*4     =    294,912
  unsigned short* hbuf = (unsigned short*)(ws + 27852800);  // 2*8192*768*2 = 25,165,824
  unsigned* barcnt     = (unsigned*)(ws + 53018624);        // 128 B

  hipMemsetAsync(barcnt, 0, 128, stream);
  k_fused<<<dim3(NBLK), dim3(256), 0, stream>>>(x, Wc, bc, wa, ba, W1, b1,
                                                gamma, beta, W2, b2,
                                                xc, w1t, scores, base, hbuf,
                                                barcnt, out);
}

// Round 13
// 169.839 us; speedup vs baseline: 2.8026x; 2.8026x over previous
//
#include <hip/hip_runtime.h>
#include <hip/hip_bf16.h>
#include <math.h>

#define S_LEN 2048
#define BATCH 4
#define HDIM 768
#define LOUT 9
#define NROWS (BATCH*S_LEN)
#define K2H 1536
#define KHALF 768
#define WIN 11
#define NEG_INF_F (-1e30f)

typedef __attribute__((ext_vector_type(4))) float f32x4;
typedef __attribute__((ext_vector_type(8))) short bf16x8;

static __device__ __forceinline__ void async_ld16(const void* g, void* l) {
  __builtin_amdgcn_global_load_lds((const __attribute__((address_space(1))) void*)g,
                                   (__attribute__((address_space(3))) void*)l, 16, 0, 0);
}

static __device__ __forceinline__ unsigned short f2bf(float f) {
  union { float f; unsigned int u; } v; v.f = f;
  unsigned int u = v.u;
  unsigned int r = (u + 0x7fffu + ((u >> 16) & 1u)) >> 16;
  return (unsigned short)r;
}

static __device__ __forceinline__ float bf2f(unsigned short h) {
  union { unsigned int u; float f; } v; v.u = ((unsigned int)h) << 16;
  return v.f;
}

// Kernel A (fused): blocks 0..1151: W1 -> W1t bf16 transpose.
//                   blocks 1152+ : wave-per-row prep (x->bf16, score, base logits).
__global__ __launch_bounds__(256) void k_prep(const float* __restrict__ W1,
                                              unsigned short* __restrict__ W1t,
                                              const float* __restrict__ x,
                                              const float* __restrict__ wa,
                                              const float* __restrict__ ba,
                                              const float* __restrict__ Wc,
                                              const float* __restrict__ bc,
                                              unsigned short* __restrict__ xc,
                                              float* __restrict__ scores,
                                              float* __restrict__ base) {
  __shared__ float tile[32][33];
  if (blockIdx.x < 1152) {
    int bk = blockIdx.x % 48;
    int bn = blockIdx.x / 48;
    int tc = threadIdx.x % 32;
    int tr = threadIdx.x / 32;
    #pragma unroll
    for (int i = 0; i < 32; i += 8) {
      tile[tr + i][tc] = W1[(bk*32 + tr + i) * HDIM + bn*32 + tc];
    }
    __syncthreads();
    #pragma unroll
    for (int i = 0; i < 32; i += 8) {
      W1t[(bn*32 + tr + i) * K2H + bk*32 + tc] = f2bf(tile[tc][tr + i]);
    }
    return;
  }
  int bid = blockIdx.x - 1152;              // 0..2047
  int lane = threadIdx.x & 63, wave = threadIdx.x >> 6;
  int row = bid * 4 + wave;                 // one wave per row
  const float* xr = x + (long)row * HDIM + lane * 12;
  float xv[12];
  { const float4 a = *(const float4*)(xr);
    const float4 b4 = *(const float4*)(xr + 4);
    const float4 c4 = *(const float4*)(xr + 8);
    xv[0]=a.x; xv[1]=a.y; xv[2]=a.z; xv[3]=a.w;
    xv[4]=b4.x; xv[5]=b4.y; xv[6]=b4.z; xv[7]=b4.w;
    xv[8]=c4.x; xv[9]=c4.y; xv[10]=c4.z; xv[11]=c4.w; }
  // bf16 cast -> first half of xc
  unsigned short* dst = xc + (long)row * K2H + lane * 12;
  #pragma unroll
  for (int q = 0; q < 3; ++q) {
    ushort4 o;
    o.x = f2bf(xv[q*4+0]); o.y = f2bf(xv[q*4+1]);
    o.z = f2bf(xv[q*4+2]); o.w = f2bf(xv[q*4+3]);
    *(ushort4*)(dst + q*4) = o;
  }
  // score partial
  const float* war = wa + lane * 12;
  float sc = 0.f;
  #pragma unroll
  for (int q = 0; q < 3; ++q) {
    const float4 w4 = *(const float4*)(war + q*4);
    sc += xv[q*4+0]*w4.x + xv[q*4+1]*w4.y + xv[q*4+2]*w4.z + xv[q*4+3]*w4.w;
  }
  // base-logit partials: lane's 12 Wc rows are contiguous (432 B)
  const float* wcr = Wc + (long)lane * 12 * LOUT;
  float p[LOUT] = {};
  #pragma unroll
  for (int j = 0; j < 12; ++j) {
    const float xj = xv[j];
    #pragma unroll
    for (int l = 0; l < LOUT; ++l) p[l] += xj * wcr[j * LOUT + l];
  }
  // one butterfly set per ROW (not per thread-triple)
  #pragma unroll
  for (int m = 1; m < 64; m <<= 1) {
    sc += __shfl_xor(sc, m);
    #pragma unroll
    for (int l = 0; l < LOUT; ++l) p[l] += __shfl_xor(p[l], m);
  }
  if (lane == 0) {
    scores[row] = sc + ba[0];
    #pragma unroll
    for (int l = 0; l < LOUT; ++l) base[row * LOUT + l] = p[l] + bc[l];
  }
}

// Kernel B: wave-per-row window softmax + weighted ctx (no shuffles, no LDS)
__global__ __launch_bounds__(256) void k_ctx(const float* __restrict__ scores,
                                             unsigned short* __restrict__ xc) {
  int lane = threadIdx.x & 63, wave = threadIdx.x >> 6;
  int row = blockIdx.x * 4 + wave;
  int b = row >> 11, s = row & 2047;
  float sw[WIN];
  int jcs[WIN];
  #pragma unroll
  for (int w = 0; w < WIN; ++w) {
    int j = s - 5 + w;
    bool valid = (j >= 0) && (j < S_LEN);
    int jc = valid ? j : (j < 0 ? 0 : S_LEN - 1);
    jcs[w] = b * S_LEN + jc;
    sw[w] = valid ? scores[b * S_LEN + jc] : NEG_INF_F;
  }
  float mx = sw[0];
  #pragma unroll
  for (int w = 1; w < WIN; ++w) mx = fmaxf(mx, sw[w]);
  float es[WIN], ssum = 0.f;
  #pragma unroll
  for (int w = 0; w < WIN; ++w) {
    es[w] = (sw[w] > -1e29f) ? __expf(sw[w] - mx) : 0.f;
    ssum += es[w];
  }
  float inv = 1.f / ssum;
  float c[12] = {};
  #pragma unroll
  for (int w = 0; w < WIN; ++w) {
    float aw = es[w] * inv;
    const unsigned short* src = xc + (long)jcs[w] * K2H + lane * 12;
    #pragma unroll
    for (int q = 0; q < 3; ++q) {
      const ushort4 uv = *(const ushort4*)(src + q*4);
      c[q*4+0] += aw * bf2f(uv.x);
      c[q*4+1] += aw * bf2f(uv.y);
      c[q*4+2] += aw * bf2f(uv.z);
      c[q*4+3] += aw * bf2f(uv.w);
    }
  }
  unsigned short* dst = xc + (long)row * K2H + HDIM + lane * 12;
  #pragma unroll
  for (int q = 0; q < 3; ++q) {
    ushort4 o;
    o.x = f2bf(c[q*4+0]); o.y = f2bf(c[q*4+1]);
    o.z = f2bf(c[q*4+2]); o.w = f2bf(c[q*4+3]);
    *(ushort4*)(dst + q*4) = o;
  }
}

// Kernel C: SPLIT-K GEMM (R9-proven). h_partial[kh] bf16.
__global__ __launch_bounds__(256, 3) void k_gemm(const unsigned short* __restrict__ A,
                                                 const unsigned short* __restrict__ Bt,
                                                 unsigned short* __restrict__ Hout) {
  __shared__ unsigned short As[2][128 * 32];
  __shared__ unsigned short Bs[2][128 * 32];
  int bid = blockIdx.x;
  int obid = (bid & 7) * 96 + (bid >> 3);
  int kh = obid / 384;
  int mt = obid % 384;
  int bm = mt / 6, bn = mt % 6;
  int t = threadIdx.x;
  int lane = t & 63, wave = t >> 6;
  int wm = wave >> 1, wn = wave & 1;

  int rowc = lane >> 2;
  int fST = ((lane >> 2) ^ (lane >> 4)) & 3;
  int sST = (lane & 3) ^ fST;
  const unsigned short* gA0 = A  + (long)(bm * 128 + wave * 16 + rowc) * K2H + kh * KHALF + sST * 8;
  const unsigned short* gB0 = Bt + (long)(bn * 128 + wave * 16 + rowc) * K2H + kh * KHALF + sST * 8;

  int fR = ((lane & 3) ^ ((lane >> 2) & 3)) & 3;
  int slR = ((lane >> 4) ^ fR) & 3;
  int arow = wm * 64 + (lane & 15);
  int brow = wn * 64 + (lane & 15);

  f32x4 acc[4][4] = {};

#define STAGE(buf, kt) do {                                                    \
    async_ld16(gA0 + (kt),            &As[buf][(wave * 16) * 32]);             \
    async_ld16(gA0 + 64 * K2H + (kt), &As[buf][(64 + wave * 16) * 32]);        \
    async_ld16(gB0 + (kt),            &Bs[buf][(wave * 16) * 32]);             \
    async_ld16(gB0 + 64 * K2H + (kt), &Bs[buf][(64 + wave * 16) * 32]);        \
  } while (0)

#define COMPUTE(buf) do {                                                      \
    bf16x8 af[4], bfv[4];                                                      \
    _Pragma("unroll")                                                          \
    for (int m = 0; m < 4; ++m)                                                \
      af[m] = *(const bf16x8*)(&As[buf][(arow + m * 16) * 32 + slR * 8]);      \
    _Pragma("unroll")                                                          \
    for (int n = 0; n < 4; ++n)                                                \
      bfv[n] = *(const bf16x8*)(&Bs[buf][(brow + n * 16) * 32 + slR * 8]);     \
    _Pragma("unroll")                                                          \
    for (int m = 0; m < 4; ++m)                                                \
      _Pragma("unroll")                                                        \
      for (int n = 0; n < 4; ++n)                                              \
        acc[m][n] = __builtin_amdgcn_mfma_f32_16x16x32_bf16(af[m], bfv[n], acc[m][n], 0, 0, 0); \
  } while (0)

  STAGE(0, 0);
  __syncthreads();
  int cur = 0;
  #pragma unroll 1
  for (int tt = 0; tt < 23; ++tt) {
    STAGE(cur ^ 1, (tt + 1) * 32);
    COMPUTE(cur);
    __syncthreads();
    cur ^= 1;
  }
  COMPUTE(cur);

  unsigned short* Hp = Hout + (long)kh * NROWS * HDIM;
  int orow = bm * 128 + wm * 64 + (lane >> 4) * 4;
  int ocol = bn * 128 + wn * 64 + (lane & 15);
  #pragma unroll
  for (int m = 0; m < 4; ++m)
    #pragma unroll
    for (int n = 0; n < 4; ++n) {
      int col = ocol + n * 16;
      #pragma unroll
      for (int r = 0; r < 4; ++r) {
        Hp[(long)(orow + m * 16 + r) * HDIM + col] = f2bf(acc[m][n][r]);
      }
    }
#undef STAGE
#undef COMPUTE
}

// Kernel D: wave-per-row: sum bf16 partials + b1, LN, exact GELU, W2, combine.
__global__ __launch_bounds__(256) void k_ln(const unsigned short* __restrict__ H0,
                                            const unsigned short* __restrict__ H1,
                                            const float* __restrict__ b1,
                                            const float* __restrict__ gamma,
                                            const float* __restrict__ beta,
                                            const float* __restrict__ W2,
                                            const float* __restrict__ b2,
                                            const float* __restrict__ base,
                                            float* __restrict__ out) {
  int lane = threadIdx.x & 63, wave = threadIdx.x >> 6;
  int row = blockIdx.x * 4 + wave;
  const unsigned short* h0p = H0 + (long)row * HDIM + lane * 12;
  const unsigned short* h1p = H1 + (long)row * HDIM + lane * 12;
  const float* b1p = b1 + lane * 12;
  float vv[12];
  #pragma unroll
  for (int q = 0; q < 3; ++q) {
    const ushort4 a = *(const ushort4*)(h0p + q*4);
    const ushort4 b4 = *(const ushort4*)(h1p + q*4);
    const float4 bb = *(const float4*)(b1p + q*4);
    vv[q*4+0] = bf2f(a.x) + bf2f(b4.x) + bb.x;
    vv[q*4+1] = bf2f(a.y) + bf2f(b4.y) + bb.y;
    vv[q*4+2] = bf2f(a.z) + bf2f(b4.z) + bb.z;
    vv[q*4+3] = bf2f(a.w) + bf2f(b4.w) + bb.w;
  }
  float s1 = 0.f, s2 = 0.f;
  #pragma unroll
  for (int j = 0; j < 12; ++j) { s1 += vv[j]; s2 += vv[j] * vv[j]; }
  #pragma unroll
  for (int m = 1; m < 64; m <<= 1) { s1 += __shfl_xor(s1, m); s2 += __shfl_xor(s2, m); }
  float mu = s1 * (1.f / HDIM);
  float var = s2 * (1.f / HDIM) - mu * mu;
  float rstd = rsqrtf(var + 1e-5f);
  const float* gp = gamma + lane * 12;
  const float* bp = beta + lane * 12;
  const float* w2r = W2 + (long)lane * 12 * LOUT;
  float p[LOUT] = {};
  #pragma unroll
  for (int q = 0; q < 3; ++q) {
    const float4 g4 = *(const float4*)(gp + q*4);
    const float4 be4 = *(const float4*)(bp + q*4);
    const float gv[4] = { g4.x, g4.y, g4.z, g4.w };
    const float bvv[4] = { be4.x, be4.y, be4.z, be4.w };
    #pragma unroll
    for (int k = 0; k < 4; ++k) {
      int j = q*4 + k;
      float g = (vv[j] - mu) * rstd * gv[k] + bvv[k];
      float gg = 0.5f * g * (1.f + erff(g * 0.70710678118654752f));
      #pragma unroll
      for (int l = 0; l < LOUT; ++l) p[l] += gg * w2r[j * LOUT + l];
    }
  }
  #pragma unroll
  for (int m = 1; m < 64; m <<= 1)
    #pragma unroll
    for (int l = 0; l < LOUT; ++l) p[l] += __shfl_xor(p[l], m);
  if (lane == 0) {
    #pragma unroll
    for (int l = 0; l < LOUT; ++l) {
      out[row * LOUT + l] = 0.5f * base[row * LOUT + l] + 0.5f * (p[l] + b2[l]);
    }
  }
}

extern "C" void kernel_launch(void* const* d_in, const int* in_sizes, int n_in,
                              void* d_out, int out_size, void* d_ws, size_t ws_size,
                              hipStream_t stream) {
  const float* x     = (const float*)d_in[0];
  const float* Wc    = (const float*)d_in[1];
  const float* bc    = (const float*)d_in[2];
  const float* wa    = (const float*)d_in[3];
  const float* ba    = (const float*)d_in[4];
  const float* W1    = (const float*)d_in[5];
  const float* b1    = (const float*)d_in[6];
  const float* gamma = (const float*)d_in[7];
  const float* beta  = (const float*)d_in[8];
  const float* W2    = (const float*)d_in[9];
  const float* b2    = (const float*)d_in[10];
  float* out = (float*)d_out;

  char* ws = (char*)d_ws;
  unsigned short* xc   = (unsigned short*)(ws);             // 8192*1536*2  = 25,165,824
  unsigned short* w1t  = (unsigned short*)(ws + 25165824);  // 768*1536*2   =  2,359,296
  float* scores        = (float*)(ws + 27525120);           // 8192*4       =     32,768
  float* base          = (float*)(ws + 27557888);           // 8192*9*4     =    294,912
  unsigned short* hbuf = (unsigned short*)(ws + 27852800);  // 2*8192*768*2 = 25,165,824

  k_prep <<<dim3(1152 + 2048), dim3(256), 0, stream>>>(W1, w1t, x, wa, ba, Wc, bc,
                                                       xc, scores, base);
  k_ctx  <<<dim3(2048), dim3(256), 0, stream>>>(scores, xc);
  k_gemm <<<dim3(768),  dim3(256), 0, stream>>>(xc, w1t, hbuf);
  k_ln   <<<dim3(2048), dim3(256), 0, stream>>>(hbuf, hbuf + (long)NROWS * HDIM, b1,
                                                gamma, beta, W2, b2, base, out);
}